// Round 23
// baseline (1121.005 us; speedup 1.0000x reference)
//
#include <hip/hip_runtime.h>
#include <hip/hip_bf16.h>

#define HDIM 128
#define G3 384          // 3*H
#define EDIM 300
#define KP 320          // K padded to 10 x 32
#define ASTRIDE 328     // A-tile LDS row stride in bf16
#define BATCH 64
#define LSTO 1024
#define QLEN 32
#define NSENT 16
#define WGB 16          // batches per scan workgroup
#define HROW 272        // padded h row bytes (17 x 16B)
#define HBUF (WGB * HROW)

#define S2F (-1.44269504088896340736f)   // -log2(e)
#define SNF (-2.88539008177792681472f)   // -2*log2(e)

typedef float4 f4;
typedef __attribute__((ext_vector_type(8))) short bf16x8;
typedef __attribute__((ext_vector_type(4))) float f32x4;

#if __has_builtin(__builtin_amdgcn_exp2f)
__device__ __forceinline__ float exp2_f(float x) { return __builtin_amdgcn_exp2f(x); }
#else
__device__ __forceinline__ float exp2_f(float x) { return exp2f(x); }
#endif
#if __has_builtin(__builtin_amdgcn_rcpf)
__device__ __forceinline__ float rcp_f(float x) { return __builtin_amdgcn_rcpf(x); }
#else
__device__ __forceinline__ float rcp_f(float x) { return 1.0f / x; }
#endif

// b = -log2e * x  ->  sigmoid(x)
__device__ __forceinline__ float sigm2(float b) { return rcp_f(1.0f + exp2_f(b)); }
// c = -2*log2e * x  ->  tanh(x) = 2/(1+2^c) - 1   (robust at saturation)
__device__ __forceinline__ float tanh2(float c) {
    return __builtin_fmaf(2.0f, rcp_f(1.0f + exp2_f(c)), -1.0f);
}

__device__ __forceinline__ float bf2f(unsigned short u) {
    return __uint_as_float(((unsigned)u) << 16);
}
__device__ __forceinline__ unsigned short f2bf_u(float f) {
    union { __hip_bfloat16 b; unsigned short s; } u;
    u.b = __float2bfloat16(f);
    return u.s;
}
__device__ __forceinline__ short f2bf_s(float f) {
    union { __hip_bfloat16 b; short s; } u;
    u.b = __float2bfloat16(f);
    return u.s;
}
__device__ __forceinline__ bf16x8 packrow8s(const float* p, float s) {
    bf16x8 v;
#pragma unroll
    for (int i = 0; i < 8; i++) v[i] = f2bf_s(p[i] * s);
    return v;
}
__device__ __forceinline__ unsigned pack2bf(float a, float b) {
    return ((unsigned)f2bf_u(b) << 16) | (unsigned)f2bf_u(a);
}
__device__ __forceinline__ void barrier_nodrain() {
    asm volatile("" ::: "memory");
    __builtin_amdgcn_s_barrier();
    asm volatile("" ::: "memory");
}
__device__ __forceinline__ void lgkm0() {
    asm volatile("s_waitcnt lgkmcnt(0)" ::: "memory");
    __builtin_amdgcn_sched_barrier(0);
}

// ---------------------------------------------------------------------------
// K0: convert w_ih (rows x 300 f32) -> wb (rows x 320 bf16, zero-padded)
// ---------------------------------------------------------------------------
__global__ __launch_bounds__(256) void k_w2bf(
    const float* __restrict__ w, __hip_bfloat16* __restrict__ wb, int rows)
{
    int i = blockIdx.x * 256 + threadIdx.x;
    if (i >= rows * KP) return;
    int r = i / KP, k = i - r * KP;
    float v = (k < EDIM) ? w[(size_t)r * EDIM + k] : 0.f;
    wb[i] = __float2bfloat16(v);
}

// ---------------------------------------------------------------------------
// K1: MFMA gather GEMM, story+question merged. Output gi scaled:
// r/z gates (g<256): S2*(b_ih+b_hh+emb.W); n gates: SN*(b_ih+emb.W).
// ---------------------------------------------------------------------------
__global__ __launch_bounds__(512) void k_gi_mfma(
    const int* __restrict__ toks_a, int nrows_a, __hip_bfloat16* __restrict__ gi_a,
    const int* __restrict__ toks_b, int nrows_b, __hip_bfloat16* __restrict__ gi_b,
    const float* __restrict__ emb,
    const __hip_bfloat16* __restrict__ wb, const float* __restrict__ b_ih,
    const float* __restrict__ b_hh)
{
    __shared__ __hip_bfloat16 a_lds[32 * ASTRIDE];
    const int tid = threadIdx.x;
    const int nb_a = nrows_a / 32;

    const int* toks;
    int nrows, rowbase;
    __hip_bfloat16* gi;
    if ((int)blockIdx.x < nb_a) {
        toks = toks_a; nrows = nrows_a; rowbase = blockIdx.x * 32; gi = gi_a;
    } else {
        toks = toks_b; nrows = nrows_b; rowbase = (blockIdx.x - nb_a) * 32; gi = gi_b;
    }

    // stage A: 32 rows x KP bf16, 4 k-elems per item (f4 load + 8B LDS store)
    for (int i = tid; i < 32 * (KP / 4); i += 512) {
        int r = i / (KP / 4), k4 = (i - r * (KP / 4)) * 4;
        int row = rowbase + r;
        f4 v = make_float4(0.f, 0.f, 0.f, 0.f);
        if (k4 < EDIM) {     // EDIM%4==0 so full f4 in-bounds
            int tok = (row < nrows) ? toks[row] : 0;
            v = *reinterpret_cast<const f4*>(emb + (size_t)tok * EDIM + k4);
        }
        uint2 pk;
        pk.x = pack2bf(v.x, v.y);
        pk.y = pack2bf(v.z, v.w);
        *reinterpret_cast<uint2*>(a_lds + r * ASTRIDE + k4) = pk;
    }
    __syncthreads();

    const int w8   = tid >> 6;
    const int l    = tid & 63;
    const int coln = l & 15;
    const int kg   = l >> 4;

    int g0 = w8 * 48 + coln, g1 = g0 + 16, g2 = g0 + 32;
    float bias0 = b_ih[g0] + (g0 < 256 ? b_hh[g0] : 0.f);
    float bias1 = b_ih[g1] + (g1 < 256 ? b_hh[g1] : 0.f);
    float bias2 = b_ih[g2] + (g2 < 256 ? b_hh[g2] : 0.f);

    f32x4 acc[2][3];
#pragma unroll
    for (int mt = 0; mt < 2; mt++) {
        acc[mt][0] = f32x4{bias0, bias0, bias0, bias0};
        acc[mt][1] = f32x4{bias1, bias1, bias1, bias1};
        acc[mt][2] = f32x4{bias2, bias2, bias2, bias2};
    }

    const __hip_bfloat16* bbase = wb + (size_t)(w8 * 48 + coln) * KP + kg * 8;
#pragma unroll
    for (int c = 0; c < KP / 32; ++c) {
        bf16x8 A0 = *reinterpret_cast<const bf16x8*>(
            a_lds + (coln) * ASTRIDE + c * 32 + kg * 8);
        bf16x8 A1 = *reinterpret_cast<const bf16x8*>(
            a_lds + (16 + coln) * ASTRIDE + c * 32 + kg * 8);
        bf16x8 B0 = *reinterpret_cast<const bf16x8*>(bbase + 0 * 16 * KP + c * 32);
        bf16x8 B1 = *reinterpret_cast<const bf16x8*>(bbase + 1 * 16 * KP + c * 32);
        bf16x8 B2 = *reinterpret_cast<const bf16x8*>(bbase + 2 * 16 * KP + c * 32);
        acc[0][0] = __builtin_amdgcn_mfma_f32_16x16x32_bf16(A0, B0, acc[0][0], 0, 0, 0);
        acc[1][0] = __builtin_amdgcn_mfma_f32_16x16x32_bf16(A1, B0, acc[1][0], 0, 0, 0);
        acc[0][1] = __builtin_amdgcn_mfma_f32_16x16x32_bf16(A0, B1, acc[0][1], 0, 0, 0);
        acc[1][1] = __builtin_amdgcn_mfma_f32_16x16x32_bf16(A1, B1, acc[1][1], 0, 0, 0);
        acc[0][2] = __builtin_amdgcn_mfma_f32_16x16x32_bf16(A0, B2, acc[0][2], 0, 0, 0);
        acc[1][2] = __builtin_amdgcn_mfma_f32_16x16x32_bf16(A1, B2, acc[1][2], 0, 0, 0);
    }

#pragma unroll
    for (int mt = 0; mt < 2; mt++) {
#pragma unroll
        for (int nt = 0; nt < 3; nt++) {
            int gate = w8 * 48 + nt * 16 + coln;
            float sc = (gate < 256) ? S2F : SNF;   // tile-uniform (16 | 256)
#pragma unroll
            for (int q = 0; q < 4; q++) {
                int row = rowbase + mt * 16 + kg * 4 + q;
                if (row < nrows)
                    gi[(size_t)row * G3 + gate] =
                        __float2bfloat16(acc[mt][nt][q] * sc);
            }
        }
    }
}

// ---------------------------------------------------------------------------
// K1b: dense variant, K = 128 (episodic gi from sents), scaled output
// ---------------------------------------------------------------------------
__global__ __launch_bounds__(192) void k_gi_dense(
    const float* __restrict__ x, int nrows,
    const float* __restrict__ w_ih, const float* __restrict__ b_ih,
    const float* __restrict__ b_hh,
    __hip_bfloat16* __restrict__ gi)
{
    __shared__ alignas(16) float a_lds[32 * HDIM];
    int tid = threadIdx.x;
    int rowbase = blockIdx.x * 32;

    for (int i = tid; i < 32 * 32; i += 192) {
        int r = i >> 5, e4 = i & 31;
        int row = rowbase + r;
        f4 v;
        if (row < nrows) v = *reinterpret_cast<const f4*>(x + (size_t)row * HDIM + e4 * 4);
        else { v.x = v.y = v.z = v.w = 0.f; }
        *reinterpret_cast<f4*>(a_lds + r * HDIM + e4 * 4) = v;
    }
    __syncthreads();

    int g0 = tid, g1 = tid + 192;
    const float* w0p = w_ih + (size_t)g0 * HDIM;
    const float* w1p = w_ih + (size_t)g1 * HDIM;
    float bb0 = b_ih[g0] + (g0 < 256 ? b_hh[g0] : 0.f);
    float bb1 = b_ih[g1] + (g1 < 256 ? b_hh[g1] : 0.f);
    float s0 = (g0 < 256) ? S2F : SNF;
    float s1 = (g1 < 256) ? S2F : SNF;

#pragma unroll
    for (int half = 0; half < 2; half++) {
        float acc0[16], acc1[16];
#pragma unroll
        for (int r = 0; r < 16; r++) { acc0[r] = 0.f; acc1[r] = 0.f; }

        for (int e4 = 0; e4 < 32; ++e4) {
            f4 w0 = *reinterpret_cast<const f4*>(w0p + e4 * 4);
            f4 w1 = *reinterpret_cast<const f4*>(w1p + e4 * 4);
#pragma unroll
            for (int r = 0; r < 16; r++) {
                f4 a = *reinterpret_cast<const f4*>(
                    a_lds + (half * 16 + r) * HDIM + e4 * 4);
                acc0[r] += a.x * w0.x + a.y * w0.y + a.z * w0.z + a.w * w0.w;
                acc1[r] += a.x * w1.x + a.y * w1.y + a.z * w1.z + a.w * w1.w;
            }
        }
#pragma unroll
        for (int r = 0; r < 16; r++) {
            int row = rowbase + half * 16 + r;
            if (row < nrows) {
                gi[(size_t)row * G3 + g0] = __float2bfloat16((acc0[r] + bb0) * s0);
                gi[(size_t)row * G3 + g1] = __float2bfloat16((acc1[r] + bb1) * s1);
            }
        }
    }
}

// ---------------------------------------------------------------------------
// scan_core: MFMA GRU recurrence, DISTANCE-2 gi prefetch: each body fully
// consumes its register set (cr/cz/cn/cm/cw) then re-issues loads for t+2
// into the SAME set late in the body -> first use trails issue by ~2 steps,
// so the compiler's vmcnt leaves HBM latency fully off the critical path.
// ---------------------------------------------------------------------------
#define SCAN_BODY(TT, TPF, RB, WB, C)                                          \
  {                                                                            \
    const int t_ = (TT);                                                       \
    bf16x8 H0 = *reinterpret_cast<const bf16x8*>(h_raw + (RB) + rd0);          \
    bf16x8 H1 = *reinterpret_cast<const bf16x8*>(h_raw + (RB) + rd1);          \
    bf16x8 H2 = *reinterpret_cast<const bf16x8*>(h_raw + (RB) + rd2);          \
    bf16x8 H3 = *reinterpret_cast<const bf16x8*>(h_raw + (RB) + rd3);          \
    f32x4 accr = {bf2f(cr##C.x), bf2f(cr##C.y), bf2f(cr##C.z), bf2f(cr##C.w)};\
    f32x4 accz = {bf2f(cz##C.x), bf2f(cz##C.y), bf2f(cz##C.z), bf2f(cz##C.w)};\
    f32x4 accnA = {bn4.x, bn4.y, bn4.z, bn4.w};                                \
    f32x4 accnB = {0.f, 0.f, 0.f, 0.f};                                        \
    float r0, r1, r2, r3, z0, z1, z2, z3;                                      \
    accr = __builtin_amdgcn_mfma_f32_16x16x32_bf16(Ar0, H0, accr, 0, 0, 0);    \
    accr = __builtin_amdgcn_mfma_f32_16x16x32_bf16(Ar1, H1, accr, 0, 0, 0);    \
    accr = __builtin_amdgcn_mfma_f32_16x16x32_bf16(Ar2, H2, accr, 0, 0, 0);    \
    accr = __builtin_amdgcn_mfma_f32_16x16x32_bf16(Ar3, H3, accr, 0, 0, 0);    \
    r0 = sigm2(accr[0]);                                                       \
    r1 = sigm2(accr[1]);                                                       \
    accz = __builtin_amdgcn_mfma_f32_16x16x32_bf16(Az0, H0, accz, 0, 0, 0);    \
    accz = __builtin_amdgcn_mfma_f32_16x16x32_bf16(Az1, H1, accz, 0, 0, 0);    \
    r2 = sigm2(accr[2]);                                                       \
    r3 = sigm2(accr[3]);                                                       \
    accz = __builtin_amdgcn_mfma_f32_16x16x32_bf16(Az2, H2, accz, 0, 0, 0);    \
    accz = __builtin_amdgcn_mfma_f32_16x16x32_bf16(Az3, H3, accz, 0, 0, 0);    \
    z0 = sigm2(accz[0]);                                                       \
    z1 = sigm2(accz[1]);                                                       \
    accnA = __builtin_amdgcn_mfma_f32_16x16x32_bf16(An0, H0, accnA, 0, 0, 0);  \
    accnB = __builtin_amdgcn_mfma_f32_16x16x32_bf16(An2, H2, accnB, 0, 0, 0);  \
    z2 = sigm2(accz[2]);                                                       \
    z3 = sigm2(accz[3]);                                                       \
    accnA = __builtin_amdgcn_mfma_f32_16x16x32_bf16(An1, H1, accnA, 0, 0, 0);  \
    accnB = __builtin_amdgcn_mfma_f32_16x16x32_bf16(An3, H3, accnB, 0, 0, 0);  \
    {                                                                          \
      float an0 = accnA[0] + accnB[0];                                         \
      float an1 = accnA[1] + accnB[1];                                         \
      float an2 = accnA[2] + accnB[2];                                         \
      float an3 = accnA[3] + accnB[3];                                         \
      float n0 = tanh2(bf2f(cn##C.x) + r0 * an0);                              \
      float n1 = tanh2(bf2f(cn##C.y) + r1 * an1);                              \
      float n2 = tanh2(bf2f(cn##C.z) + r2 * an2);                              \
      float n3 = tanh2(bf2f(cn##C.w) + r3 * an3);                              \
      float h0 = n0 + z0 * (hp0 - n0);                                         \
      float h1 = n1 + z1 * (hp1 - n1);                                         \
      float h2 = n2 + z2 * (hp2 - n2);                                         \
      float h3 = n3 + z3 * (hp3 - n3);                                         \
      if (MODE == 2) {                                                         \
        h0 = hp0 + cw##C * (h0 - hp0);                                         \
        h1 = hp1 + cw##C * (h1 - hp1);                                         \
        h2 = hp2 + cw##C * (h2 - hp2);                                         \
        h3 = hp3 + cw##C * (h3 - hp3);                                         \
      }                                                                        \
      hp0 = h0; hp1 = h1; hp2 = h2; hp3 = h3;                                  \
    }                                                                          \
    if (MODE == 0) {                                                           \
      if (cm##C) {                                                             \
        if (scnt < NSENT) {                                                    \
          float4 v_ = make_float4(hp0, hp1, hp2, hp3);                         \
          *reinterpret_cast<float4*>(                                          \
              sents + ((size_t)bb * NSENT + scnt) * HDIM + j0) = v_;           \
        }                                                                      \
        scnt++;                                                                \
      }                                                                        \
    }                                                                          \
    if (MODE == 1 && t_ == qi) {                                               \
      float4 v_ = make_float4(hp0, hp1, hp2, hp3);                             \
      *reinterpret_cast<float4*>(qv_out + bb * HDIM + j0) = v_;                \
      *reinterpret_cast<float4*>(q_ws + bb * HDIM + j0) = v_;                  \
    }                                                                          \
    if (MODE == 2 && t_ == T - 1) {                                            \
      float4 v_ = make_float4(hp0, hp1, hp2, hp3);                             \
      *reinterpret_cast<float4*>(mem_lds + col * HDIM + j0) = v_;              \
      if (ep_out)                                                              \
        *reinterpret_cast<float4*>(ep_out + bb * HDIM + j0) = v_;              \
    }                                                                          \
    {   /* re-issue prefetch for t+2 into the SAME (fully consumed) set */     \
      int tp_ = (TPF);                                                         \
      if (tp_ >= T) tp_ = T - 1;                                               \
      const unsigned short* gp =                                               \
          reinterpret_cast<const unsigned short*>(gib + (size_t)tp_ * G3);     \
      cr##C = *reinterpret_cast<const ushort4*>(gp + j0);                      \
      cz##C = *reinterpret_cast<const ushort4*>(gp + 128 + j0);                \
      cn##C = *reinterpret_cast<const ushort4*>(gp + 256 + j0);                \
      if (MODE == 0) cm##C = mask[bb * LSTO + tp_];                            \
      if (MODE == 2) cw##C = gsrc[tp_];                                        \
    }                                                                          \
    {                                                                          \
      uint2 hw_;                                                               \
      hw_.x = pack2bf(hp0, hp1);                                               \
      hw_.y = pack2bf(hp2, hp3);                                               \
      *reinterpret_cast<uint2*>(h_raw + (WB) + wroff) = hw_;                   \
    }                                                                          \
    lgkm0();                                                                   \
    barrier_nodrain();                                                         \
  }

template <int MODE>
__device__ __forceinline__ void scan_core(
    const __hip_bfloat16* __restrict__ gi, int T,
    const float* __restrict__ w_hh, const float* __restrict__ b_hh,
    const int* __restrict__ mask, float* __restrict__ sents,
    const int* __restrict__ qtoks, float* __restrict__ qv_out,
    float* __restrict__ q_ws,
    const float* __restrict__ gl_lds,      // MODE2: [16 batch][16 t] LDS
    float* __restrict__ ep_out,            // MODE2 (nullable)
    float* __restrict__ mem_lds,           // MODE2: [16][128] f32 LDS
    int b0, unsigned char* __restrict__ h_raw)
{
    const int tid = threadIdx.x;
    const int w   = tid >> 6;
    const int l   = tid & 63;
    const int col = l & 15;
    const int kg  = l >> 4;
    const int bb  = b0 + col;
    const int j0  = 16 * w + 4 * kg;

    const float* wr = w_hh + (size_t)(16 * w + col) * HDIM + kg * 8;
    const float* wz = w_hh + (size_t)(128 + 16 * w + col) * HDIM + kg * 8;
    const float* wn = w_hh + (size_t)(256 + 16 * w + col) * HDIM + kg * 8;
    bf16x8 Ar0 = packrow8s(wr +  0, S2F), Ar1 = packrow8s(wr + 32, S2F),
           Ar2 = packrow8s(wr + 64, S2F), Ar3 = packrow8s(wr + 96, S2F);
    bf16x8 Az0 = packrow8s(wz +  0, S2F), Az1 = packrow8s(wz + 32, S2F),
           Az2 = packrow8s(wz + 64, S2F), Az3 = packrow8s(wz + 96, S2F);
    bf16x8 An0 = packrow8s(wn +  0, SNF), An1 = packrow8s(wn + 32, SNF),
           An2 = packrow8s(wn + 64, SNF), An3 = packrow8s(wn + 96, SNF);
    asm volatile("" : "+v"(Ar0), "+v"(Ar1), "+v"(Ar2), "+v"(Ar3));
    asm volatile("" : "+v"(Az0), "+v"(Az1), "+v"(Az2), "+v"(Az3));
    asm volatile("" : "+v"(An0), "+v"(An1), "+v"(An2), "+v"(An3));

    f4 bnl = *reinterpret_cast<const f4*>(b_hh + 256 + j0);
    f4 bn4 = make_float4(bnl.x * SNF, bnl.y * SNF, bnl.z * SNF, bnl.w * SNF);
    const float* gsrc = (MODE == 2) ? (gl_lds + col * NSENT) : nullptr;

    const int rd0 = col * HROW + 0 * 64 + kg * 16;
    const int rd1 = col * HROW + 1 * 64 + kg * 16;
    const int rd2 = col * HROW + 2 * 64 + kg * 16;
    const int rd3 = col * HROW + 3 * 64 + kg * 16;
    const int wroff = col * HROW + j0 * 2;

    for (int i = tid; i < 2 * HBUF / 4; i += 512)
        reinterpret_cast<unsigned*>(h_raw)[i] = 0u;

    int qi = QLEN - 1;
    if (MODE == 1) {
        for (int t2 = 0; t2 < QLEN - 1; t2++)
            if (qtoks[bb * QLEN + t2 + 1] == 0) { qi = t2; break; }
    }
    int scnt = 0;

    const __hip_bfloat16* gib = gi + (size_t)bb * T * G3;
    ushort4 crA, czA, cnA, crB, czB, cnB;
    int cmA = 0, cmB = 0;
    float cwA = 0.f, cwB = 0.f;
    __syncthreads();   // h_raw zero + (MODE2) gl/mem_lds ready before reads
    {   // preload t=0 -> set A, t=1 -> set B
        const unsigned short* gp = reinterpret_cast<const unsigned short*>(gib);
        crA = *reinterpret_cast<const ushort4*>(gp + j0);
        czA = *reinterpret_cast<const ushort4*>(gp + 128 + j0);
        cnA = *reinterpret_cast<const ushort4*>(gp + 256 + j0);
        if (MODE == 0) cmA = mask[bb * LSTO];
        if (MODE == 2) cwA = gsrc[0];
        int t1 = (T > 1) ? 1 : 0;
        const unsigned short* gq =
            reinterpret_cast<const unsigned short*>(gib + (size_t)t1 * G3);
        crB = *reinterpret_cast<const ushort4*>(gq + j0);
        czB = *reinterpret_cast<const ushort4*>(gq + 128 + j0);
        cnB = *reinterpret_cast<const ushort4*>(gq + 256 + j0);
        if (MODE == 0) cmB = mask[bb * LSTO + t1];
        if (MODE == 2) cwB = gsrc[t1];
    }
    float hp0 = 0.f, hp1 = 0.f, hp2 = 0.f, hp3 = 0.f;
    __syncthreads();

    for (int t = 0; t < T; t += 2) {
        SCAN_BODY(t,     t + 2, 0,    HBUF, A)
        SCAN_BODY(t + 1, t + 3, HBUF, 0,    B)
    }
}

// ---------------------------------------------------------------------------
// K2a: combined story + question scans. Grid = 8 WGs x 512:
// blocks 0-3 -> story b0=bid*16; blocks 4-7 -> question b0=(bid-4)*16.
// ---------------------------------------------------------------------------
__global__ __launch_bounds__(512, 1) void k_scan01(
    const __hip_bfloat16* __restrict__ gi_sto,
    const __hip_bfloat16* __restrict__ gi_q,
    const float* __restrict__ w_hh, const float* __restrict__ b_hh,
    const int* __restrict__ mask, float* __restrict__ sents,
    const int* __restrict__ qtoks, float* __restrict__ qv_out,
    float* __restrict__ q_ws)
{
    __shared__ alignas(16) unsigned char h_raw[2 * HBUF];
    if (blockIdx.x < 4) {
        scan_core<0>(gi_sto, LSTO, w_hh, b_hh, mask, sents,
                     nullptr, nullptr, nullptr, nullptr, nullptr, nullptr,
                     blockIdx.x * WGB, h_raw);
    } else {
        scan_core<1>(gi_q, QLEN, w_hh, b_hh, nullptr, nullptr,
                     qtoks, qv_out, q_ws, nullptr, nullptr, nullptr,
                     (blockIdx.x - 4) * WGB, h_raw);
    }
}

// ---------------------------------------------------------------------------
// K2b: fused episodic module: 3 x (gates + 16-step scan) in one launch.
// ---------------------------------------------------------------------------
__global__ __launch_bounds__(512, 1) void k_ep(
    const __hip_bfloat16* __restrict__ gi_ep,
    const float* __restrict__ w_hh, const float* __restrict__ b_hh,
    const float* __restrict__ sents, const float* __restrict__ q_ws,
    const float* __restrict__ gate_w, const float* __restrict__ gate_b,
    float* __restrict__ out_g, float* __restrict__ out_ep)
{
    __shared__ alignas(16) unsigned char h_raw[2 * HBUF];
    __shared__ float gl[WGB * NSENT];
    __shared__ alignas(16) float mem_lds[WGB * HDIM];

    const int tid = threadIdx.x;
    const int b0 = blockIdx.x * WGB;
    const float gb0 = gate_b[0];

    for (int it = 0; it < 3; ++it) {
        if (tid < 256) {
            int bq = tid >> 4, tq = tid & 15;
            int b = b0 + bq;
            const float* sv = sents + ((size_t)b * NSENT + tq) * HDIM;
            const float* Qv = q_ws + (size_t)b * HDIM;
            const float* Mv = mem_lds + bq * HDIM;
            float p = 0.f;
            for (int j4 = 0; j4 < HDIM / 4; j4++) {
                f4 S = *reinterpret_cast<const f4*>(sv + j4 * 4);
                f4 Q = *reinterpret_cast<const f4*>(Qv + j4 * 4);
                f4 M;
                if (it == 0) M = Q;
                else M = *reinterpret_cast<const f4*>(Mv + j4 * 4);
                f4 w0 = *reinterpret_cast<const f4*>(gate_w + j4 * 4);
                f4 w1 = *reinterpret_cast<const f4*>(gate_w + HDIM + j4 * 4);
                f4 w2 = *reinterpret_cast<const f4*>(gate_w + 2 * HDIM + j4 * 4);
                f4 w3 = *reinterpret_cast<const f4*>(gate_w + 3 * HDIM + j4 * 4);
                float dqx = S.x - Q.x, dqy = S.y - Q.y, dqz = S.z - Q.z, dqw = S.w - Q.w;
                float dmx = S.x - M.x, dmy = S.y - M.y, dmz = S.z - M.z, dmw = S.w - M.w;
                p += (S.x * Q.x) * w0.x + (S.y * Q.y) * w0.y +
                     (S.z * Q.z) * w0.z + (S.w * Q.w) * w0.w;
                p += (S.x * M.x) * w1.x + (S.y * M.y) * w1.y +
                     (S.z * M.z) * w1.z + (S.w * M.w) * w1.w;
                p += (dqx * dqx) * w2.x + (dqy * dqy) * w2.y +
                     (dqz * dqz) * w2.z + (dqw * dqw) * w2.w;
                p += (dmx * dmx) * w3.x + (dmy * dmy) * w3.y +
                     (dmz * dmz) * w3.z + (dmw * dmw) * w3.w;
            }
            float g = sigm2(S2F * (p + gb0));
            gl[bq * NSENT + tq] = g;
            if (it == 2) out_g[b * NSENT + tq] = g;
        }
        // scan_core's first __syncthreads makes gl visible to all waves
        scan_core<2>(gi_ep, NSENT, w_hh, b_hh, nullptr, nullptr,
                     nullptr, nullptr, nullptr, gl,
                     (it == 2) ? out_ep : nullptr, mem_lds,
                     b0, h_raw);
        __syncthreads();
    }
}

// ---------------------------------------------------------------------------
extern "C" void kernel_launch(void* const* d_in, const int* in_sizes, int n_in,
                              void* d_out, int out_size, void* d_ws, size_t ws_size,
                              hipStream_t stream)
{
    const int*   x_sto    = (const int*)d_in[0];
    const int*   x_mask   = (const int*)d_in[1];
    const int*   x_q      = (const int*)d_in[2];
    const float* emb      = (const float*)d_in[4];
    const float* enc_w_ih = (const float*)d_in[5];
    const float* enc_w_hh = (const float*)d_in[6];
    const float* enc_b_ih = (const float*)d_in[7];
    const float* enc_b_hh = (const float*)d_in[8];
    const float* gate_w   = (const float*)d_in[9];
    const float* gate_b   = (const float*)d_in[10];
    const float* ep_w_ih  = (const float*)d_in[11];
    const float* ep_w_hh  = (const float*)d_in[12];
    const float* ep_b_ih  = (const float*)d_in[13];
    const float* ep_b_hh  = (const float*)d_in[14];

    float* out_q  = (float*)d_out;                       // (64,128)
    float* out_ep = (float*)d_out + BATCH * HDIM;        // (1,64,128)
    float* out_g  = (float*)d_out + 2 * BATCH * HDIM;    // (64,16)

    char* ws = (char*)d_ws;
    size_t off = 0;
    auto alloc = [&](size_t bytes) {
        void* p = ws + off;
        off += (bytes + 255) & ~(size_t)255;
        return p;
    };
    __hip_bfloat16* gi_sto = (__hip_bfloat16*)alloc((size_t)BATCH * LSTO * G3 * 2);
    __hip_bfloat16* gi_q   = (__hip_bfloat16*)alloc((size_t)BATCH * QLEN * G3 * 2);
    __hip_bfloat16* gi_ep  = (__hip_bfloat16*)alloc((size_t)BATCH * NSENT * G3 * 2);
    __hip_bfloat16* wb_enc = (__hip_bfloat16*)alloc((size_t)G3 * KP * 2);
    float* sents    = (float*)alloc((size_t)BATCH * NSENT * HDIM * 4);
    float* q_ws     = (float*)alloc((size_t)BATCH * HDIM * 4);
    (void)ws_size; (void)in_sizes; (void)n_in; (void)out_size;

    // A0: convert enc_w_ih to padded bf16
    k_w2bf<<<(G3 * KP + 255) / 256, 256, 0, stream>>>(enc_w_ih, wb_enc, G3);

    // A: story + question input projections, one merged MFMA launch
    k_gi_mfma<<<(BATCH * LSTO) / 32 + (BATCH * QLEN) / 32, 512, 0, stream>>>(
        x_sto, BATCH * LSTO, gi_sto, x_q, BATCH * QLEN, gi_q,
        emb, wb_enc, enc_b_ih, enc_b_hh);

    // B: story + question scans in one launch (8 WGs)
    k_scan01<<<8, 512, 0, stream>>>(
        gi_sto, gi_q, enc_w_hh, enc_b_hh, x_mask, sents, x_q, out_q, q_ws);

    // C: episodic gi, then the fused 3-iteration episodic module
    k_gi_dense<<<(BATCH * NSENT) / 32, 192, 0, stream>>>(
        sents, BATCH * NSENT, ep_w_ih, ep_b_ih, ep_b_hh, gi_ep);
    k_ep<<<BATCH / WGB, 512, 0, stream>>>(
        gi_ep, ep_w_hh, ep_b_hh, sents, q_ws, gate_w, gate_b, out_g, out_ep);
}

// Round 24
// 1107.372 us; speedup vs baseline: 1.0123x; 1.0123x over previous
//
#include <hip/hip_runtime.h>
#include <hip/hip_bf16.h>

#define HDIM 128
#define G3 384          // 3*H
#define EDIM 300
#define KP 320          // K padded to 10 x 32
#define ASTRIDE 328     // A-tile LDS row stride in bf16
#define BATCH 64
#define LSTO 1024
#define QLEN 32
#define NSENT 16
#define WGB 16          // batches per scan workgroup
#define HROW 272        // padded h row bytes (17 x 16B)
#define HBUF (WGB * HROW)

#define S2F (-1.44269504088896340736f)   // -log2(e)
#define SNF (-2.88539008177792681472f)   // -2*log2(e)

typedef float4 f4;
typedef __attribute__((ext_vector_type(8))) short bf16x8;
typedef __attribute__((ext_vector_type(4))) float f32x4;

#if __has_builtin(__builtin_amdgcn_exp2f)
__device__ __forceinline__ float exp2_f(float x) { return __builtin_amdgcn_exp2f(x); }
#else
__device__ __forceinline__ float exp2_f(float x) { return exp2f(x); }
#endif
#if __has_builtin(__builtin_amdgcn_rcpf)
__device__ __forceinline__ float rcp_f(float x) { return __builtin_amdgcn_rcpf(x); }
#else
__device__ __forceinline__ float rcp_f(float x) { return 1.0f / x; }
#endif

// b = -log2e * x  ->  sigmoid(x)
__device__ __forceinline__ float sigm2(float b) { return rcp_f(1.0f + exp2_f(b)); }
// c = -2*log2e * x  ->  tanh(x) = 2/(1+2^c) - 1   (robust at saturation)
__device__ __forceinline__ float tanh2(float c) {
    return __builtin_fmaf(2.0f, rcp_f(1.0f + exp2_f(c)), -1.0f);
}

__device__ __forceinline__ float bf2f(unsigned short u) {
    return __uint_as_float(((unsigned)u) << 16);
}
__device__ __forceinline__ unsigned short f2bf_u(float f) {
    union { __hip_bfloat16 b; unsigned short s; } u;
    u.b = __float2bfloat16(f);
    return u.s;
}
__device__ __forceinline__ short f2bf_s(float f) {
    union { __hip_bfloat16 b; short s; } u;
    u.b = __float2bfloat16(f);
    return u.s;
}
__device__ __forceinline__ bf16x8 packrow8s(const float* p, float s) {
    bf16x8 v;
#pragma unroll
    for (int i = 0; i < 8; i++) v[i] = f2bf_s(p[i] * s);
    return v;
}
__device__ __forceinline__ unsigned pack2bf(float a, float b) {
    return ((unsigned)f2bf_u(b) << 16) | (unsigned)f2bf_u(a);
}
__device__ __forceinline__ void barrier_nodrain() {
    asm volatile("" ::: "memory");
    __builtin_amdgcn_s_barrier();
    asm volatile("" ::: "memory");
}
__device__ __forceinline__ void lgkm0() {
    asm volatile("s_waitcnt lgkmcnt(0)" ::: "memory");
    __builtin_amdgcn_sched_barrier(0);
}

// ---------------------------------------------------------------------------
// K0: convert w_ih (rows x 300 f32) -> wb (rows x 320 bf16, zero-padded)
// ---------------------------------------------------------------------------
__global__ __launch_bounds__(256) void k_w2bf(
    const float* __restrict__ w, __hip_bfloat16* __restrict__ wb, int rows)
{
    int i = blockIdx.x * 256 + threadIdx.x;
    if (i >= rows * KP) return;
    int r = i / KP, k = i - r * KP;
    float v = (k < EDIM) ? w[(size_t)r * EDIM + k] : 0.f;
    wb[i] = __float2bfloat16(v);
}

// ---------------------------------------------------------------------------
// K1: MFMA gather GEMM, story+question merged. Output gi scaled:
// r/z gates (g<256): S2*(b_ih+b_hh+emb.W); n gates: SN*(b_ih+emb.W).
// ---------------------------------------------------------------------------
__global__ __launch_bounds__(512) void k_gi_mfma(
    const int* __restrict__ toks_a, int nrows_a, __hip_bfloat16* __restrict__ gi_a,
    const int* __restrict__ toks_b, int nrows_b, __hip_bfloat16* __restrict__ gi_b,
    const float* __restrict__ emb,
    const __hip_bfloat16* __restrict__ wb, const float* __restrict__ b_ih,
    const float* __restrict__ b_hh)
{
    __shared__ __hip_bfloat16 a_lds[32 * ASTRIDE];
    const int tid = threadIdx.x;
    const int nb_a = nrows_a / 32;

    const int* toks;
    int nrows, rowbase;
    __hip_bfloat16* gi;
    if ((int)blockIdx.x < nb_a) {
        toks = toks_a; nrows = nrows_a; rowbase = blockIdx.x * 32; gi = gi_a;
    } else {
        toks = toks_b; nrows = nrows_b; rowbase = (blockIdx.x - nb_a) * 32; gi = gi_b;
    }

    // stage A: 32 rows x KP bf16, 4 k-elems per item (f4 load + 8B LDS store)
    for (int i = tid; i < 32 * (KP / 4); i += 512) {
        int r = i / (KP / 4), k4 = (i - r * (KP / 4)) * 4;
        int row = rowbase + r;
        f4 v = make_float4(0.f, 0.f, 0.f, 0.f);
        if (k4 < EDIM) {     // EDIM%4==0 so full f4 in-bounds
            int tok = (row < nrows) ? toks[row] : 0;
            v = *reinterpret_cast<const f4*>(emb + (size_t)tok * EDIM + k4);
        }
        uint2 pk;
        pk.x = pack2bf(v.x, v.y);
        pk.y = pack2bf(v.z, v.w);
        *reinterpret_cast<uint2*>(a_lds + r * ASTRIDE + k4) = pk;
    }
    __syncthreads();

    const int w8   = tid >> 6;
    const int l    = tid & 63;
    const int coln = l & 15;
    const int kg   = l >> 4;

    int g0 = w8 * 48 + coln, g1 = g0 + 16, g2 = g0 + 32;
    float bias0 = b_ih[g0] + (g0 < 256 ? b_hh[g0] : 0.f);
    float bias1 = b_ih[g1] + (g1 < 256 ? b_hh[g1] : 0.f);
    float bias2 = b_ih[g2] + (g2 < 256 ? b_hh[g2] : 0.f);

    f32x4 acc[2][3];
#pragma unroll
    for (int mt = 0; mt < 2; mt++) {
        acc[mt][0] = f32x4{bias0, bias0, bias0, bias0};
        acc[mt][1] = f32x4{bias1, bias1, bias1, bias1};
        acc[mt][2] = f32x4{bias2, bias2, bias2, bias2};
    }

    const __hip_bfloat16* bbase = wb + (size_t)(w8 * 48 + coln) * KP + kg * 8;
#pragma unroll
    for (int c = 0; c < KP / 32; ++c) {
        bf16x8 A0 = *reinterpret_cast<const bf16x8*>(
            a_lds + (coln) * ASTRIDE + c * 32 + kg * 8);
        bf16x8 A1 = *reinterpret_cast<const bf16x8*>(
            a_lds + (16 + coln) * ASTRIDE + c * 32 + kg * 8);
        bf16x8 B0 = *reinterpret_cast<const bf16x8*>(bbase + 0 * 16 * KP + c * 32);
        bf16x8 B1 = *reinterpret_cast<const bf16x8*>(bbase + 1 * 16 * KP + c * 32);
        bf16x8 B2 = *reinterpret_cast<const bf16x8*>(bbase + 2 * 16 * KP + c * 32);
        acc[0][0] = __builtin_amdgcn_mfma_f32_16x16x32_bf16(A0, B0, acc[0][0], 0, 0, 0);
        acc[1][0] = __builtin_amdgcn_mfma_f32_16x16x32_bf16(A1, B0, acc[1][0], 0, 0, 0);
        acc[0][1] = __builtin_amdgcn_mfma_f32_16x16x32_bf16(A0, B1, acc[0][1], 0, 0, 0);
        acc[1][1] = __builtin_amdgcn_mfma_f32_16x16x32_bf16(A1, B1, acc[1][1], 0, 0, 0);
        acc[0][2] = __builtin_amdgcn_mfma_f32_16x16x32_bf16(A0, B2, acc[0][2], 0, 0, 0);
        acc[1][2] = __builtin_amdgcn_mfma_f32_16x16x32_bf16(A1, B2, acc[1][2], 0, 0, 0);
    }

#pragma unroll
    for (int mt = 0; mt < 2; mt++) {
#pragma unroll
        for (int nt = 0; nt < 3; nt++) {
            int gate = w8 * 48 + nt * 16 + coln;
            float sc = (gate < 256) ? S2F : SNF;   // tile-uniform (16 | 256)
#pragma unroll
            for (int q = 0; q < 4; q++) {
                int row = rowbase + mt * 16 + kg * 4 + q;
                if (row < nrows)
                    gi[(size_t)row * G3 + gate] =
                        __float2bfloat16(acc[mt][nt][q] * sc);
            }
        }
    }
}

// ---------------------------------------------------------------------------
// K1b: dense variant, K = 128 (episodic gi from sents), scaled output
// ---------------------------------------------------------------------------
__global__ __launch_bounds__(192) void k_gi_dense(
    const float* __restrict__ x, int nrows,
    const float* __restrict__ w_ih, const float* __restrict__ b_ih,
    const float* __restrict__ b_hh,
    __hip_bfloat16* __restrict__ gi)
{
    __shared__ alignas(16) float a_lds[32 * HDIM];
    int tid = threadIdx.x;
    int rowbase = blockIdx.x * 32;

    for (int i = tid; i < 32 * 32; i += 192) {
        int r = i >> 5, e4 = i & 31;
        int row = rowbase + r;
        f4 v;
        if (row < nrows) v = *reinterpret_cast<const f4*>(x + (size_t)row * HDIM + e4 * 4);
        else { v.x = v.y = v.z = v.w = 0.f; }
        *reinterpret_cast<f4*>(a_lds + r * HDIM + e4 * 4) = v;
    }
    __syncthreads();

    int g0 = tid, g1 = tid + 192;
    const float* w0p = w_ih + (size_t)g0 * HDIM;
    const float* w1p = w_ih + (size_t)g1 * HDIM;
    float bb0 = b_ih[g0] + (g0 < 256 ? b_hh[g0] : 0.f);
    float bb1 = b_ih[g1] + (g1 < 256 ? b_hh[g1] : 0.f);
    float s0 = (g0 < 256) ? S2F : SNF;
    float s1 = (g1 < 256) ? S2F : SNF;

#pragma unroll
    for (int half = 0; half < 2; half++) {
        float acc0[16], acc1[16];
#pragma unroll
        for (int r = 0; r < 16; r++) { acc0[r] = 0.f; acc1[r] = 0.f; }

        for (int e4 = 0; e4 < 32; ++e4) {
            f4 w0 = *reinterpret_cast<const f4*>(w0p + e4 * 4);
            f4 w1 = *reinterpret_cast<const f4*>(w1p + e4 * 4);
#pragma unroll
            for (int r = 0; r < 16; r++) {
                f4 a = *reinterpret_cast<const f4*>(
                    a_lds + (half * 16 + r) * HDIM + e4 * 4);
                acc0[r] += a.x * w0.x + a.y * w0.y + a.z * w0.z + a.w * w0.w;
                acc1[r] += a.x * w1.x + a.y * w1.y + a.z * w1.z + a.w * w1.w;
            }
        }
#pragma unroll
        for (int r = 0; r < 16; r++) {
            int row = rowbase + half * 16 + r;
            if (row < nrows) {
                gi[(size_t)row * G3 + g0] = __float2bfloat16((acc0[r] + bb0) * s0);
                gi[(size_t)row * G3 + g1] = __float2bfloat16((acc1[r] + bb1) * s1);
            }
        }
    }
}

// ---------------------------------------------------------------------------
// scan_core: MFMA GRU recurrence, critical-path-shortened MFMA schedule:
// all-accr first (r-sigmoid overlaps remaining 8 MFMAs), all-accz next
// (z overlaps accn), accn as TWO parallel 2-deep chains (+1 add).
// Distance-1 A/B prefetch (measured best: r21/r22 = 886 us).
// ---------------------------------------------------------------------------
#define SCAN_BODY(TT, TPF, RB, WB, C, P)                                       \
  {                                                                            \
    const int t_ = (TT);                                                       \
    bf16x8 H0 = *reinterpret_cast<const bf16x8*>(h_raw + (RB) + rd0);          \
    bf16x8 H1 = *reinterpret_cast<const bf16x8*>(h_raw + (RB) + rd1);          \
    bf16x8 H2 = *reinterpret_cast<const bf16x8*>(h_raw + (RB) + rd2);          \
    bf16x8 H3 = *reinterpret_cast<const bf16x8*>(h_raw + (RB) + rd3);          \
    {                                                                          \
      const int tp_ = (TPF);                                                   \
      const unsigned short* gp =                                               \
          reinterpret_cast<const unsigned short*>(gib + (size_t)tp_ * G3);     \
      cr##P = *reinterpret_cast<const ushort4*>(gp + j0);                      \
      cz##P = *reinterpret_cast<const ushort4*>(gp + 128 + j0);                \
      cn##P = *reinterpret_cast<const ushort4*>(gp + 256 + j0);                \
      if (MODE == 0) cm##P = mask[bb * LSTO + tp_];                            \
      if (MODE == 2) cw##P = gsrc[tp_];                                        \
    }                                                                          \
    f32x4 accr = {bf2f(cr##C.x), bf2f(cr##C.y), bf2f(cr##C.z), bf2f(cr##C.w)};\
    f32x4 accz = {bf2f(cz##C.x), bf2f(cz##C.y), bf2f(cz##C.z), bf2f(cz##C.w)};\
    f32x4 accnA = {bn4.x, bn4.y, bn4.z, bn4.w};                                \
    f32x4 accnB = {0.f, 0.f, 0.f, 0.f};                                        \
    float r0, r1, r2, r3, z0, z1, z2, z3;                                      \
    __builtin_amdgcn_s_setprio(1);                                             \
    accr = __builtin_amdgcn_mfma_f32_16x16x32_bf16(Ar0, H0, accr, 0, 0, 0);    \
    accr = __builtin_amdgcn_mfma_f32_16x16x32_bf16(Ar1, H1, accr, 0, 0, 0);    \
    accr = __builtin_amdgcn_mfma_f32_16x16x32_bf16(Ar2, H2, accr, 0, 0, 0);    \
    accr = __builtin_amdgcn_mfma_f32_16x16x32_bf16(Ar3, H3, accr, 0, 0, 0);    \
    r0 = sigm2(accr[0]);                                                       \
    r1 = sigm2(accr[1]);                                                       \
    accz = __builtin_amdgcn_mfma_f32_16x16x32_bf16(Az0, H0, accz, 0, 0, 0);    \
    accz = __builtin_amdgcn_mfma_f32_16x16x32_bf16(Az1, H1, accz, 0, 0, 0);    \
    r2 = sigm2(accr[2]);                                                       \
    r3 = sigm2(accr[3]);                                                       \
    accz = __builtin_amdgcn_mfma_f32_16x16x32_bf16(Az2, H2, accz, 0, 0, 0);    \
    accz = __builtin_amdgcn_mfma_f32_16x16x32_bf16(Az3, H3, accz, 0, 0, 0);    \
    z0 = sigm2(accz[0]);                                                       \
    z1 = sigm2(accz[1]);                                                       \
    accnA = __builtin_amdgcn_mfma_f32_16x16x32_bf16(An0, H0, accnA, 0, 0, 0);  \
    accnB = __builtin_amdgcn_mfma_f32_16x16x32_bf16(An2, H2, accnB, 0, 0, 0);  \
    z2 = sigm2(accz[2]);                                                       \
    z3 = sigm2(accz[3]);                                                       \
    accnA = __builtin_amdgcn_mfma_f32_16x16x32_bf16(An1, H1, accnA, 0, 0, 0);  \
    accnB = __builtin_amdgcn_mfma_f32_16x16x32_bf16(An3, H3, accnB, 0, 0, 0);  \
    __builtin_amdgcn_s_setprio(0);                                             \
    {                                                                          \
      float an0 = accnA[0] + accnB[0];                                         \
      float an1 = accnA[1] + accnB[1];                                         \
      float an2 = accnA[2] + accnB[2];                                         \
      float an3 = accnA[3] + accnB[3];                                         \
      float n0 = tanh2(bf2f(cn##C.x) + r0 * an0);                              \
      float n1 = tanh2(bf2f(cn##C.y) + r1 * an1);                              \
      float n2 = tanh2(bf2f(cn##C.z) + r2 * an2);                              \
      float n3 = tanh2(bf2f(cn##C.w) + r3 * an3);                              \
      float h0 = n0 + z0 * (hp0 - n0);                                         \
      float h1 = n1 + z1 * (hp1 - n1);                                         \
      float h2 = n2 + z2 * (hp2 - n2);                                         \
      float h3 = n3 + z3 * (hp3 - n3);                                         \
      if (MODE == 2) {                                                         \
        h0 = hp0 + cw##C * (h0 - hp0);                                         \
        h1 = hp1 + cw##C * (h1 - hp1);                                         \
        h2 = hp2 + cw##C * (h2 - hp2);                                         \
        h3 = hp3 + cw##C * (h3 - hp3);                                         \
      }                                                                        \
      hp0 = h0; hp1 = h1; hp2 = h2; hp3 = h3;                                  \
    }                                                                          \
    {                                                                          \
      uint2 hw_;                                                               \
      hw_.x = pack2bf(hp0, hp1);                                               \
      hw_.y = pack2bf(hp2, hp3);                                               \
      *reinterpret_cast<uint2*>(h_raw + (WB) + wroff) = hw_;                   \
    }                                                                          \
    if (MODE == 0) {                                                           \
      if (cm##C) {                                                             \
        if (scnt < NSENT) {                                                    \
          float4 v_ = make_float4(hp0, hp1, hp2, hp3);                         \
          *reinterpret_cast<float4*>(                                          \
              sents + ((size_t)bb * NSENT + scnt) * HDIM + j0) = v_;           \
        }                                                                      \
        scnt++;                                                                \
      }                                                                        \
    }                                                                          \
    if (MODE == 1 && t_ == qi) {                                               \
      float4 v_ = make_float4(hp0, hp1, hp2, hp3);                             \
      *reinterpret_cast<float4*>(qv_out + bb * HDIM + j0) = v_;                \
      *reinterpret_cast<float4*>(q_ws + bb * HDIM + j0) = v_;                  \
    }                                                                          \
    if (MODE == 2 && t_ == T - 1) {                                            \
      float4 v_ = make_float4(hp0, hp1, hp2, hp3);                             \
      *reinterpret_cast<float4*>(mem_lds + col * HDIM + j0) = v_;              \
      if (ep_out)                                                              \
        *reinterpret_cast<float4*>(ep_out + bb * HDIM + j0) = v_;              \
    }                                                                          \
    lgkm0();                                                                   \
    barrier_nodrain();                                                         \
  }

template <int MODE>
__device__ __forceinline__ void scan_core(
    const __hip_bfloat16* __restrict__ gi, int T,
    const float* __restrict__ w_hh, const float* __restrict__ b_hh,
    const int* __restrict__ mask, float* __restrict__ sents,
    const int* __restrict__ qtoks, float* __restrict__ qv_out,
    float* __restrict__ q_ws,
    const float* __restrict__ gl_lds,      // MODE2: [16 batch][16 t] LDS
    float* __restrict__ ep_out,            // MODE2 (nullable)
    float* __restrict__ mem_lds,           // MODE2: [16][128] f32 LDS
    int b0, unsigned char* __restrict__ h_raw)
{
    const int tid = threadIdx.x;
    const int w   = tid >> 6;
    const int l   = tid & 63;
    const int col = l & 15;
    const int kg  = l >> 4;
    const int bb  = b0 + col;
    const int j0  = 16 * w + 4 * kg;

    const float* wr = w_hh + (size_t)(16 * w + col) * HDIM + kg * 8;
    const float* wz = w_hh + (size_t)(128 + 16 * w + col) * HDIM + kg * 8;
    const float* wn = w_hh + (size_t)(256 + 16 * w + col) * HDIM + kg * 8;
    bf16x8 Ar0 = packrow8s(wr +  0, S2F), Ar1 = packrow8s(wr + 32, S2F),
           Ar2 = packrow8s(wr + 64, S2F), Ar3 = packrow8s(wr + 96, S2F);
    bf16x8 Az0 = packrow8s(wz +  0, S2F), Az1 = packrow8s(wz + 32, S2F),
           Az2 = packrow8s(wz + 64, S2F), Az3 = packrow8s(wz + 96, S2F);
    bf16x8 An0 = packrow8s(wn +  0, SNF), An1 = packrow8s(wn + 32, SNF),
           An2 = packrow8s(wn + 64, SNF), An3 = packrow8s(wn + 96, SNF);
    asm volatile("" : "+v"(Ar0), "+v"(Ar1), "+v"(Ar2), "+v"(Ar3));
    asm volatile("" : "+v"(Az0), "+v"(Az1), "+v"(Az2), "+v"(Az3));
    asm volatile("" : "+v"(An0), "+v"(An1), "+v"(An2), "+v"(An3));

    f4 bnl = *reinterpret_cast<const f4*>(b_hh + 256 + j0);
    f4 bn4 = make_float4(bnl.x * SNF, bnl.y * SNF, bnl.z * SNF, bnl.w * SNF);
    const float* gsrc = (MODE == 2) ? (gl_lds + col * NSENT) : nullptr;

    const int rd0 = col * HROW + 0 * 64 + kg * 16;
    const int rd1 = col * HROW + 1 * 64 + kg * 16;
    const int rd2 = col * HROW + 2 * 64 + kg * 16;
    const int rd3 = col * HROW + 3 * 64 + kg * 16;
    const int wroff = col * HROW + j0 * 2;

    for (int i = tid; i < 2 * HBUF / 4; i += 512)
        reinterpret_cast<unsigned*>(h_raw)[i] = 0u;

    int qi = QLEN - 1;
    if (MODE == 1) {
        for (int t2 = 0; t2 < QLEN - 1; t2++)
            if (qtoks[bb * QLEN + t2 + 1] == 0) { qi = t2; break; }
    }
    int scnt = 0;

    const __hip_bfloat16* gib = gi + (size_t)bb * T * G3;
    ushort4 crA, czA, cnA, crB, czB, cnB;
    int cmA = 0, cmB = 0;
    float cwA = 0.f, cwB = 0.f;
    __syncthreads();   // h_raw zero + (MODE2) gl/mem_lds ready before reads
    {
        const unsigned short* gp = reinterpret_cast<const unsigned short*>(gib);
        crA = *reinterpret_cast<const ushort4*>(gp + j0);
        czA = *reinterpret_cast<const ushort4*>(gp + 128 + j0);
        cnA = *reinterpret_cast<const ushort4*>(gp + 256 + j0);
        if (MODE == 0) cmA = mask[bb * LSTO];
        if (MODE == 2) cwA = gsrc[0];
    }
    float hp0 = 0.f, hp1 = 0.f, hp2 = 0.f, hp3 = 0.f;
    __syncthreads();

    for (int t = 0; t < T; t += 2) {
        SCAN_BODY(t,     t + 1,                       0,    HBUF, A, B)
        SCAN_BODY(t + 1, (t + 2 < T ? t + 2 : t + 1), HBUF, 0,    B, A)
    }
}

// ---------------------------------------------------------------------------
// K2a: combined story + question scans. Grid = 8 WGs x 512:
// blocks 0-3 -> story b0=bid*16; blocks 4-7 -> question b0=(bid-4)*16.
// ---------------------------------------------------------------------------
__global__ __launch_bounds__(512, 1) void k_scan01(
    const __hip_bfloat16* __restrict__ gi_sto,
    const __hip_bfloat16* __restrict__ gi_q,
    const float* __restrict__ w_hh, const float* __restrict__ b_hh,
    const int* __restrict__ mask, float* __restrict__ sents,
    const int* __restrict__ qtoks, float* __restrict__ qv_out,
    float* __restrict__ q_ws)
{
    __shared__ alignas(16) unsigned char h_raw[2 * HBUF];
    if (blockIdx.x < 4) {
        scan_core<0>(gi_sto, LSTO, w_hh, b_hh, mask, sents,
                     nullptr, nullptr, nullptr, nullptr, nullptr, nullptr,
                     blockIdx.x * WGB, h_raw);
    } else {
        scan_core<1>(gi_q, QLEN, w_hh, b_hh, nullptr, nullptr,
                     qtoks, qv_out, q_ws, nullptr, nullptr, nullptr,
                     (blockIdx.x - 4) * WGB, h_raw);
    }
}

// ---------------------------------------------------------------------------
// K2b: fused episodic module: 3 x (gates + 16-step scan) in one launch.
// ---------------------------------------------------------------------------
__global__ __launch_bounds__(512, 1) void k_ep(
    const __hip_bfloat16* __restrict__ gi_ep,
    const float* __restrict__ w_hh, const float* __restrict__ b_hh,
    const float* __restrict__ sents, const float* __restrict__ q_ws,
    const float* __restrict__ gate_w, const float* __restrict__ gate_b,
    float* __restrict__ out_g, float* __restrict__ out_ep)
{
    __shared__ alignas(16) unsigned char h_raw[2 * HBUF];
    __shared__ float gl[WGB * NSENT];
    __shared__ alignas(16) float mem_lds[WGB * HDIM];

    const int tid = threadIdx.x;
    const int b0 = blockIdx.x * WGB;
    const float gb0 = gate_b[0];

    for (int it = 0; it < 3; ++it) {
        if (tid < 256) {
            int bq = tid >> 4, tq = tid & 15;
            int b = b0 + bq;
            const float* sv = sents + ((size_t)b * NSENT + tq) * HDIM;
            const float* Qv = q_ws + (size_t)b * HDIM;
            const float* Mv = mem_lds + bq * HDIM;
            float p = 0.f;
            for (int j4 = 0; j4 < HDIM / 4; j4++) {
                f4 S = *reinterpret_cast<const f4*>(sv + j4 * 4);
                f4 Q = *reinterpret_cast<const f4*>(Qv + j4 * 4);
                f4 M;
                if (it == 0) M = Q;
                else M = *reinterpret_cast<const f4*>(Mv + j4 * 4);
                f4 w0 = *reinterpret_cast<const f4*>(gate_w + j4 * 4);
                f4 w1 = *reinterpret_cast<const f4*>(gate_w + HDIM + j4 * 4);
                f4 w2 = *reinterpret_cast<const f4*>(gate_w + 2 * HDIM + j4 * 4);
                f4 w3 = *reinterpret_cast<const f4*>(gate_w + 3 * HDIM + j4 * 4);
                float dqx = S.x - Q.x, dqy = S.y - Q.y, dqz = S.z - Q.z, dqw = S.w - Q.w;
                float dmx = S.x - M.x, dmy = S.y - M.y, dmz = S.z - M.z, dmw = S.w - M.w;
                p += (S.x * Q.x) * w0.x + (S.y * Q.y) * w0.y +
                     (S.z * Q.z) * w0.z + (S.w * Q.w) * w0.w;
                p += (S.x * M.x) * w1.x + (S.y * M.y) * w1.y +
                     (S.z * M.z) * w1.z + (S.w * M.w) * w1.w;
                p += (dqx * dqx) * w2.x + (dqy * dqy) * w2.y +
                     (dqz * dqz) * w2.z + (dqw * dqw) * w2.w;
                p += (dmx * dmx) * w3.x + (dmy * dmy) * w3.y +
                     (dmz * dmz) * w3.z + (dmw * dmw) * w3.w;
            }
            float g = sigm2(S2F * (p + gb0));
            gl[bq * NSENT + tq] = g;
            if (it == 2) out_g[b * NSENT + tq] = g;
        }
        // scan_core's first __syncthreads makes gl visible to all waves
        scan_core<2>(gi_ep, NSENT, w_hh, b_hh, nullptr, nullptr,
                     nullptr, nullptr, nullptr, gl,
                     (it == 2) ? out_ep : nullptr, mem_lds,
                     b0, h_raw);
        __syncthreads();
    }
}

// ---------------------------------------------------------------------------
extern "C" void kernel_launch(void* const* d_in, const int* in_sizes, int n_in,
                              void* d_out, int out_size, void* d_ws, size_t ws_size,
                              hipStream_t stream)
{
    const int*   x_sto    = (const int*)d_in[0];
    const int*   x_mask   = (const int*)d_in[1];
    const int*   x_q      = (const int*)d_in[2];
    const float* emb      = (const float*)d_in[4];
    const float* enc_w_ih = (const float*)d_in[5];
    const float* enc_w_hh = (const float*)d_in[6];
    const float* enc_b_ih = (const float*)d_in[7];
    const float* enc_b_hh = (const float*)d_in[8];
    const float* gate_w   = (const float*)d_in[9];
    const float* gate_b   = (const float*)d_in[10];
    const float* ep_w_ih  = (const float*)d_in[11];
    const float* ep_w_hh  = (const float*)d_in[12];
    const float* ep_b_ih  = (const float*)d_in[13];
    const float* ep_b_hh  = (const float*)d_in[14];

    float* out_q  = (float*)d_out;                       // (64,128)
    float* out_ep = (float*)d_out + BATCH * HDIM;        // (1,64,128)
    float* out_g  = (float*)d_out + 2 * BATCH * HDIM;    // (64,16)

    char* ws = (char*)d_ws;
    size_t off = 0;
    auto alloc = [&](size_t bytes) {
        void* p = ws + off;
        off += (bytes + 255) & ~(size_t)255;
        return p;
    };
    __hip_bfloat16* gi_sto = (__hip_bfloat16*)alloc((size_t)BATCH * LSTO * G3 * 2);
    __hip_bfloat16* gi_q   = (__hip_bfloat16*)alloc((size_t)BATCH * QLEN * G3 * 2);
    __hip_bfloat16* gi_ep  = (__hip_bfloat16*)alloc((size_t)BATCH * NSENT * G3 * 2);
    __hip_bfloat16* wb_enc = (__hip_bfloat16*)alloc((size_t)G3 * KP * 2);
    float* sents    = (float*)alloc((size_t)BATCH * NSENT * HDIM * 4);
    float* q_ws     = (float*)alloc((size_t)BATCH * HDIM * 4);
    (void)ws_size; (void)in_sizes; (void)n_in; (void)out_size;

    // A0: convert enc_w_ih to padded bf16
    k_w2bf<<<(G3 * KP + 255) / 256, 256, 0, stream>>>(enc_w_ih, wb_enc, G3);

    // A: story + question input projections, one merged MFMA launch
    k_gi_mfma<<<(BATCH * LSTO) / 32 + (BATCH * QLEN) / 32, 512, 0, stream>>>(
        x_sto, BATCH * LSTO, gi_sto, x_q, BATCH * QLEN, gi_q,
        emb, wb_enc, enc_b_ih, enc_b_hh);

    // B: story + question scans in one launch (8 WGs)
    k_scan01<<<8, 512, 0, stream>>>(
        gi_sto, gi_q, enc_w_hh, enc_b_hh, x_mask, sents, x_q, out_q, q_ws);

    // C: episodic gi, then the fused 3-iteration episodic module
    k_gi_dense<<<(BATCH * NSENT) / 32, 192, 0, stream>>>(
        sents, BATCH * NSENT, ep_w_ih, ep_b_ih, ep_b_hh, gi_ep);
    k_ep<<<BATCH / WGB, 512, 0, stream>>>(
        gi_ep, ep_w_hh, ep_b_hh, sents, q_ws, gate_w, gate_b, out_g, out_ep);
}